// Round 6
// baseline (223.360 us; speedup 1.0000x reference)
//
#include <hip/hip_runtime.h>
#include <stdint.h>

#define BN 16384
#define DK 1024
#define CN 100
#define CP 112              // padded col count
#define CP2 224             // hi cols [0,112) + lo cols [112,224) in wB
#define ROWS 32             // rows per block (2 waves x 16)
#define THREADS 128
#define KS 32               // K per step
#define NSTEP (DK / KS)
#define STEPE (CP2 * KS)    // elements per K-step block in wB = 7168
#define GP 112              // g_buf pitch (bf16 elements)
#define PSB 64              // psum blocks
#define PSROWS (BN / PSB)   // 256 rows per psum block

typedef __attribute__((ext_vector_type(4))) float f32x4;
typedef __attribute__((ext_vector_type(8))) short bf16x8;
typedef unsigned short ushort_t;
typedef unsigned int uint_t;

__device__ __forceinline__ ushort_t f2bf(float f) {
    uint_t u = __float_as_uint(f);
    uint_t r = u + 0x7FFFu + ((u >> 16) & 1u);   // RNE
    return (ushort_t)(r >> 16);
}
__device__ __forceinline__ float bf2f(ushort_t h) {
    return __uint_as_float(((uint_t)h) << 16);
}
__device__ __forceinline__ float getf(const float4& v, int e) {
    return e == 0 ? v.x : e == 1 ? v.y : e == 2 ? v.z : v.w;
}

// ---------------- prep: W -> wB K-blocked [st][c][kk], hi/lo bf16; + inits ----------------
__global__ __launch_bounds__(256) void k_prep(const float* __restrict__ W,
        ushort_t* __restrict__ wB, unsigned long long* __restrict__ packed,
        int* __restrict__ counts, float* ce_sum, float* term_sum, int* present) {
    __shared__ float tile[8][CN];
    const int tid = threadIdx.x;
    const int b = blockIdx.x;              // 0..127
    const int st = b >> 2, kq8 = (b & 3) * 8;
    const float* src = W + (size_t)(st * KS + kq8) * CN;   // 800 contiguous floats
    for (int i = tid; i < 8 * CN; i += 256) {
        int kk = i / CN;
        tile[kk][i - kk * CN] = src[i];
    }
    __syncthreads();
    for (int j = tid; j < CP * 8; j += 256) {
        int c = j >> 3, kk = j & 7;
        float v = (c < CN) ? tile[kk][c] : 0.f;
        ushort_t hb = f2bf(v);
        ushort_t lb = f2bf(v - bf2f(hb));
        size_t o = (size_t)st * STEPE + (size_t)c * KS + kq8 + kk;
        wB[o] = hb;
        wB[o + (size_t)CP * KS] = lb;
    }
    if (b == 0) {
        if (tid < CN) { packed[tid] = ~0ULL; counts[tid] = 0; }
        if (tid == 0) { *ce_sum = 0.f; *term_sum = 0.f; *present = 0; }
    }
}

// ---------------- main: x@W (MFMA, hi/lo, no LDS/barriers) + softmax + g/ce/anchor ----------------
__global__ __launch_bounds__(THREADS) void k_main(
    const float* __restrict__ x, const ushort_t* __restrict__ wB,
    const int* __restrict__ y, ushort_t* __restrict__ g_buf,
    unsigned long long* __restrict__ packed, int* __restrict__ counts,
    float* __restrict__ ce_sum) {

    __shared__ float red[THREADS];
    const int tid = threadIdx.x;
    const int lane = tid & 63;
    const int wv = tid >> 6;              // 0..1
    const int l15 = lane & 15;
    const int lg = lane >> 4;             // 0..3
    const int row0 = blockIdx.x * ROWS;

    // per-lane A source: row = row0 + wv*16 + l15, k base = lg*8
    const float* xg = x + (size_t)(row0 + wv * 16 + l15) * DK + lg * 8;
    // per-lane B source: col = t*16 + l15, k base = lg*8 (+st*STEPE)
    const ushort_t* wg = wB + (size_t)l15 * KS + lg * 8;

    float4 xpa[4], xpb[4];                // x prefetch, depth 4
    bf16x8 bh[2][7], bl[2][7];            // B prefetch, depth 2 (16B fragments)

#pragma unroll
    for (int s = 0; s < 4; ++s) {
        xpa[s] = *(const float4*)(xg + s * KS);
        xpb[s] = *(const float4*)(xg + s * KS + 4);
    }
#pragma unroll
    for (int s = 0; s < 2; ++s)
#pragma unroll
        for (int t = 0; t < 7; ++t) {
            const ushort_t* p = wg + (size_t)s * STEPE + t * (16 * KS);
            bh[s][t] = *(const bf16x8*)p;
            bl[s][t] = *(const bf16x8*)(p + CP * KS);
        }

    f32x4 acc[7];
#pragma unroll
    for (int t = 0; t < 7; ++t) acc[t] = (f32x4){0.f, 0.f, 0.f, 0.f};

#pragma unroll
    for (int st = 0; st < NSTEP; ++st) {
        // grab current B regs, then refill slot with st+2
        bf16x8 cbh[7], cbl[7];
#pragma unroll
        for (int t = 0; t < 7; ++t) { cbh[t] = bh[st & 1][t]; cbl[t] = bl[st & 1][t]; }
        if (st + 2 < NSTEP) {
#pragma unroll
            for (int t = 0; t < 7; ++t) {
                const ushort_t* p = wg + (size_t)(st + 2) * STEPE + t * (16 * KS);
                bh[st & 1][t] = *(const bf16x8*)p;
                bl[st & 1][t] = *(const bf16x8*)(p + CP * KS);
            }
        }
        // convert current A (8 floats -> hi/lo bf16), then refill slot with st+4
        bf16x8 ah, al;
#pragma unroll
        for (int e = 0; e < 4; ++e) {
            float f0 = getf(xpa[st & 3], e);
            float f1 = getf(xpb[st & 3], e);
            ushort_t h0 = f2bf(f0), h1 = f2bf(f1);
            ushort_t l0 = f2bf(f0 - bf2f(h0)), l1 = f2bf(f1 - bf2f(h1));
            ah[e] = (short)h0; ah[e + 4] = (short)h1;
            al[e] = (short)l0; al[e + 4] = (short)l1;
        }
        if (st + 4 < NSTEP) {
            xpa[st & 3] = *(const float4*)(xg + (st + 4) * KS);
            xpb[st & 3] = *(const float4*)(xg + (st + 4) * KS + 4);
        }
#pragma unroll
        for (int t = 0; t < 7; ++t) {
            acc[t] = __builtin_amdgcn_mfma_f32_16x16x32_bf16(ah, cbh[t], acc[t], 0, 0, 0);
            acc[t] = __builtin_amdgcn_mfma_f32_16x16x32_bf16(ah, cbl[t], acc[t], 0, 0, 0);
            acc[t] = __builtin_amdgcn_mfma_f32_16x16x32_bf16(al, cbh[t], acc[t], 0, 0, 0);
        }
    }

    // epilogue: softmax per row. lane's rows: wv*16 + lg*4 + rr ; cols l15+16t
    float ce_acc = 0.f;
#pragma unroll
    for (int rr = 0; rr < 4; ++rr) {
        const int grow = row0 + wv * 16 + lg * 4 + rr;
        const int yr = y[grow];
        float m = -3.4e38f;
#pragma unroll
        for (int t = 0; t < 7; ++t) {
            int c = l15 + 16 * t;
            if (c < CN) m = fmaxf(m, acc[t][rr]);
        }
#pragma unroll
        for (int s = 1; s < 16; s <<= 1) m = fmaxf(m, __shfl_xor(m, s));
        float ev[7], ssum = 0.f;
#pragma unroll
        for (int t = 0; t < 7; ++t) {
            int c = l15 + 16 * t;
            ev[t] = (c < CN) ? __expf(acc[t][rr] - m) : 0.f;
            ssum += ev[t];
        }
#pragma unroll
        for (int s = 1; s < 16; s <<= 1) ssum += __shfl_xor(ssum, s);
        const float lse = m + __logf(ssum);
        const float inv = 1.f / ssum;
#pragma unroll
        for (int t = 0; t < 7; ++t) {
            int c = l15 + 16 * t;
            float g = (c < CN) ? (ev[t] * inv - ((c == yr) ? 1.f : 0.f)) : 0.f;
            g_buf[(size_t)grow * GP + c] = f2bf(g);
            if (c == yr) {
                float ce = lse - acc[t][rr];
                ce_acc += ce;
                unsigned long long pk =
                    ((unsigned long long)__float_as_uint(fmaxf(ce, 0.f)) << 32) |
                    (unsigned int)grow;
                atomicMin(&packed[yr], pk);   // argmin ce; ties -> lowest row idx
                atomicAdd(&counts[yr], 1);
            }
        }
    }
    red[tid] = ce_acc;
    __syncthreads();
    for (int s = 64; s > 0; s >>= 1) {
        if (tid < s) red[tid] += red[tid + s];
        __syncthreads();
    }
    if (tid == 0) atomicAdd(ce_sum, red[0]);
}

// ---------------- Gram: M = W^T W (112x112 fp32), K split over 4 waves ----------------
__global__ __launch_bounds__(256) void k_gram(const ushort_t* __restrict__ wB,
                                              float* __restrict__ M) {
    __shared__ float gacc[4][64][4];
    const int tid = threadIdx.x;
    const int lane = tid & 63, wvv = tid >> 6;
    const int c1t = blockIdx.x / 7, c2t = blockIdx.x % 7;
    const int l15 = lane & 15, lg = lane >> 4;
    const ushort_t* pa = wB + (size_t)(c1t * 16 + l15) * KS + lg * 8;
    const ushort_t* pb = wB + (size_t)(c2t * 16 + l15) * KS + lg * 8;
    f32x4 acc = (f32x4){0.f, 0.f, 0.f, 0.f};
#pragma unroll
    for (int i = 0; i < 8; ++i) {
        const size_t o = (size_t)(wvv * 8 + i) * STEPE;
        bf16x8 ah = *(const bf16x8*)(pa + o);
        bf16x8 al = *(const bf16x8*)(pa + o + CP * KS);
        bf16x8 bh = *(const bf16x8*)(pb + o);
        bf16x8 bl = *(const bf16x8*)(pb + o + CP * KS);
        acc = __builtin_amdgcn_mfma_f32_16x16x32_bf16(ah, bh, acc, 0, 0, 0);
        acc = __builtin_amdgcn_mfma_f32_16x16x32_bf16(ah, bl, acc, 0, 0, 0);
        acc = __builtin_amdgcn_mfma_f32_16x16x32_bf16(al, bh, acc, 0, 0, 0);
    }
#pragma unroll
    for (int e = 0; e < 4; ++e) gacc[wvv][lane][e] = acc[e];
    __syncthreads();
    if (tid < 64) {
#pragma unroll
        for (int e = 0; e < 4; ++e) {
            float s = gacc[0][tid][e] + gacc[1][tid][e] + gacc[2][tid][e] + gacc[3][tid][e];
            int row = (tid >> 4) * 4 + e, col = tid & 15;
            M[(size_t)(c1t * 16 + row) * CP + c2t * 16 + col] = s;
        }
    }
}

// ---------------- partial class sums (segment reduction, stage 1) ----------------
__global__ __launch_bounds__(256) void k_psum(const int* __restrict__ y,
        const ushort_t* __restrict__ g_buf, float* __restrict__ partial) {
    __shared__ float acc[2][CN][CP];   // 89.6 KB
    const int tid = threadIdx.x;
    const int team = tid >> 7, j = tid & 127;
    float* af = (float*)acc;
    for (int i = tid; i < 2 * CN * CP; i += 256) af[i] = 0.f;
    __syncthreads();
    const int row0 = blockIdx.x * PSROWS;
    for (int it = 0; it < PSROWS / 2; ++it) {
        const int row = row0 + it * 2 + team;
        const int cls = y[row];
        if (j < CP) acc[team][cls][j] += bf2f(g_buf[(size_t)row * GP + j]);
    }
    __syncthreads();
    float* out = partial + (size_t)blockIdx.x * (CN * CP);
    for (int i = tid; i < CN * CP; i += 256) out[i] = af[i] + af[i + CN * CP];
}

// ---------------- reduce partials -> class_sum ----------------
__global__ __launch_bounds__(256) void k_reduce(const float* __restrict__ partial,
                                                float* __restrict__ cls) {
    const int i = blockIdx.x * 256 + threadIdx.x;
    if (i >= CN * CP) return;
    float s = 0.f;
#pragma unroll 4
    for (int b = 0; b < PSB; ++b) s += partial[(size_t)b * (CN * CP) + i];
    cls[i] = s;
}

// ---------------- per-class cosines via symmetric Gram matrix ----------------
__global__ __launch_bounds__(128) void k_class(
    const float* __restrict__ M, const ushort_t* __restrict__ g_buf,
    const float* __restrict__ cls, const int* __restrict__ counts,
    const unsigned long long* __restrict__ packed,
    float* __restrict__ term_sum, int* __restrict__ present) {
    __shared__ float a_s[CP], p_s[CP], n_s[CP];
    __shared__ float wsum[2][5];
    const int c = blockIdx.x, t = threadIdx.x;
    if (counts[c] == 0) return;
    const int anchor = (int)(packed[c] & 0xffffffffULL);
    if (t < CP) {
        float a = bf2f(g_buf[(size_t)anchor * GP + t]);
        float cs = cls[c * CP + t];
        float tot = 0.f;
#pragma unroll 4
        for (int k = 0; k < CN; ++k) tot += cls[k * CP + t];   // coalesced
        a_s[t] = a; p_s[t] = cs - a; n_s[t] = tot - cs;
    }
    __syncthreads();
    float aa = 0, ap = 0, pp = 0, an = 0, nn = 0;
    if (t < CP) {
        float ua = 0, up = 0, un = 0;
#pragma unroll 4
        for (int k = 0; k < CP; ++k) {
            float m = M[(size_t)k * CP + t];   // M symmetric -> coalesced rows
            ua = fmaf(m, a_s[k], ua);
            up = fmaf(m, p_s[k], up);
            un = fmaf(m, n_s[k], un);
        }
        aa = a_s[t] * ua; ap = a_s[t] * up; pp = p_s[t] * up;
        an = a_s[t] * un; nn = n_s[t] * un;
    }
#pragma unroll
    for (int s = 1; s < 64; s <<= 1) {
        aa += __shfl_xor(aa, s); ap += __shfl_xor(ap, s); pp += __shfl_xor(pp, s);
        an += __shfl_xor(an, s); nn += __shfl_xor(nn, s);
    }
    const int wid = t >> 6;
    if ((t & 63) == 0) {
        wsum[wid][0] = aa; wsum[wid][1] = ap; wsum[wid][2] = pp;
        wsum[wid][3] = an; wsum[wid][4] = nn;
    }
    __syncthreads();
    if (t == 0) {
        aa = wsum[0][0] + wsum[1][0];
        ap = wsum[0][1] + wsum[1][1];
        pp = wsum[0][2] + wsum[1][2];
        an = wsum[0][3] + wsum[1][3];
        nn = wsum[0][4] + wsum[1][4];
        float na  = sqrtf(fmaxf(aa, 0.f));
        float np_ = sqrtf(fmaxf(pp, 0.f));
        float nn_ = sqrtf(fmaxf(nn, 0.f));
        float cos_ap = ap / (fmaxf(na, 1e-12f) * fmaxf(np_, 1e-12f));
        float cos_an = an / (fmaxf(na, 1e-12f) * fmaxf(nn_, 1e-12f));
        atomicAdd(term_sum, cos_ap - cos_an);
        atomicAdd(present, 1);
    }
}

// ---------------- final scalar ----------------
__global__ void k_final(const float* ce_sum, const float* term_sum,
                        const int* present, float* out) {
    float npres = fmaxf((float)(*present), 1.f);
    out[0] = (*ce_sum) * (1.f / (float)BN) - 2.0f * ((*term_sum) / npres);
}

extern "C" void kernel_launch(void* const* d_in, const int* in_sizes, int n_in,
                              void* d_out, int out_size, void* d_ws, size_t ws_size,
                              hipStream_t stream) {
    const float* x = (const float*)d_in[0];
    const float* W = (const float*)d_in[1];
    const int* y = (const int*)d_in[2];

    char* ws = (char*)d_ws;
    ushort_t* wB      = (ushort_t*)(ws);                    // 458752 B
    ushort_t* g_buf   = (ushort_t*)(ws + 458752);           // 3670016 B
    float*    partial = (float*)(ws + 4128768);             // 2867200 B
    float*    cls     = (float*)(ws + 6995968);             // 44800 B
    float*    M       = (float*)(ws + 7040768);             // 50176 B
    unsigned long long* packed = (unsigned long long*)(ws + 7090944);  // 800 B
    int*      counts  = (int*)(ws + 7091744);               // 400 B
    float*    ce_sum  = (float*)(ws + 7092144);
    float*    term_sum= (float*)(ws + 7092148);
    int*      present = (int*)(ws + 7092152);

    k_prep<<<128, 256, 0, stream>>>(W, wB, packed, counts, ce_sum, term_sum, present);
    k_main<<<BN / ROWS, THREADS, 0, stream>>>(x, wB, y, g_buf, packed, counts, ce_sum);
    k_gram<<<49, 256, 0, stream>>>(wB, M);
    k_psum<<<PSB, 256, 0, stream>>>(y, g_buf, partial);
    k_reduce<<<(CN * CP + 255) / 256, 256, 0, stream>>>(partial, cls);
    k_class<<<CN, 128, 0, stream>>>(M, g_buf, cls, counts, packed, term_sum, present);
    k_final<<<1, 1, 0, stream>>>(ce_sum, term_sum, present, (float*)d_out);
}

// Round 7
// 181.854 us; speedup vs baseline: 1.2282x; 1.2282x over previous
//
#include <hip/hip_runtime.h>
#include <stdint.h>

#define BN 16384
#define DK 1024
#define CN 100
#define CP 112              // padded col count
#define CP2 224             // hi cols [0,112) + lo cols [112,224) in wB
#define THREADS 256
#define KS 32               // K per step
#define NSTEP (DK / KS)
#define KSPLIT 4            // waves per block, disjoint K quarters
#define WK (DK / KSPLIT)    // 256 K per wave
#define WSTEP (WK / KS)     // 8 steps per wave
#define STEPE (CP2 * KS)    // elements per K-step block in wB = 7168
#define GP 112              // g_buf pitch (bf16 elements)
#define PSB 64              // psum blocks
#define PSR (BN / PSB)      // 256 rows per psum block (128 per team)

typedef __attribute__((ext_vector_type(4))) float f32x4;
typedef __attribute__((ext_vector_type(8))) short bf16x8;
typedef unsigned short ushort_t;
typedef unsigned int uint_t;

__device__ __forceinline__ ushort_t f2bf(float f) {
    uint_t u = __float_as_uint(f);
    uint_t r = u + 0x7FFFu + ((u >> 16) & 1u);   // RNE
    return (ushort_t)(r >> 16);
}
__device__ __forceinline__ float bf2f(ushort_t h) {
    return __uint_as_float(((uint_t)h) << 16);
}
__device__ __forceinline__ float getf(const float4& v, int e) {
    return e == 0 ? v.x : e == 1 ? v.y : e == 2 ? v.z : v.w;
}

// ---------------- prep: W -> wB K-blocked [st][c][kk], hi/lo bf16; + inits ----------------
__global__ __launch_bounds__(256) void k_prep(const float* __restrict__ W,
        ushort_t* __restrict__ wB, unsigned long long* __restrict__ packed,
        int* __restrict__ counts, float* ce_sum, float* term_sum, int* present) {
    __shared__ float tile[8][CN];
    const int tid = threadIdx.x;
    const int b = blockIdx.x;              // 0..127
    const int st = b >> 2, kq8 = (b & 3) * 8;
    const float* src = W + (size_t)(st * KS + kq8) * CN;   // 800 contiguous floats
    for (int i = tid; i < 8 * CN; i += 256) {
        int kk = i / CN;
        tile[kk][i - kk * CN] = src[i];
    }
    __syncthreads();
    for (int j = tid; j < CP * 8; j += 256) {
        int c = j >> 3, kk = j & 7;
        float v = (c < CN) ? tile[kk][c] : 0.f;
        ushort_t hb = f2bf(v);
        ushort_t lb = f2bf(v - bf2f(hb));
        size_t o = (size_t)st * STEPE + (size_t)c * KS + kq8 + kk;
        wB[o] = hb;
        wB[o + (size_t)CP * KS] = lb;
    }
    if (b == 0) {
        if (tid < CN) { packed[tid] = ~0ULL; counts[tid] = 0; }
        if (tid == 0) { *ce_sum = 0.f; *term_sum = 0.f; *present = 0; }
    }
}

// ---------------- main: x@W, K split over 4 waves, LDS combine + epilogue ----------------
__global__ __launch_bounds__(THREADS) void k_main(
    const float* __restrict__ x, const ushort_t* __restrict__ wB,
    const int* __restrict__ y, ushort_t* __restrict__ g_buf,
    unsigned long long* __restrict__ packed, int* __restrict__ counts,
    float* __restrict__ ce_sum) {

    __shared__ float cacc[KSPLIT][64][29];   // +1 pad (stride 29) -> conflict-free

    const int tid = threadIdx.x;
    const int lane = tid & 63;
    const int wv = tid >> 6;              // K-quarter 0..3
    const int l15 = lane & 15;
    const int lg = lane >> 4;             // 0..3
    const int row0 = blockIdx.x * 16;

    // A source: row = row0 + l15, k = wv*WK + st*KS + lg*8
    const float* xg = x + (size_t)(row0 + l15) * DK + wv * WK + lg * 8;
    // B source: col = t*16 + l15, same k; hi plane only
    const ushort_t* wg = wB + (size_t)(wv * WSTEP) * STEPE + (size_t)l15 * KS + lg * 8;

    f32x4 acc[7];
#pragma unroll
    for (int t = 0; t < 7; ++t) acc[t] = (f32x4){0.f, 0.f, 0.f, 0.f};

#pragma unroll
    for (int s = 0; s < WSTEP; ++s) {
        float4 xa = *(const float4*)(xg + s * KS);
        float4 xb = *(const float4*)(xg + s * KS + 4);
        bf16x8 ah, al;
#pragma unroll
        for (int e = 0; e < 4; ++e) {
            float f0 = getf(xa, e);
            float f1 = getf(xb, e);
            ushort_t h0 = f2bf(f0), h1 = f2bf(f1);
            ushort_t l0 = f2bf(f0 - bf2f(h0)), l1 = f2bf(f1 - bf2f(h1));
            ah[e] = (short)h0; ah[e + 4] = (short)h1;
            al[e] = (short)l0; al[e + 4] = (short)l1;
        }
        const ushort_t* bp = wg + (size_t)s * STEPE;
#pragma unroll
        for (int t = 0; t < 7; ++t) {
            bf16x8 bh = *(const bf16x8*)(bp + t * (16 * KS));
            acc[t] = __builtin_amdgcn_mfma_f32_16x16x32_bf16(ah, bh, acc[t], 0, 0, 0);
            acc[t] = __builtin_amdgcn_mfma_f32_16x16x32_bf16(al, bh, acc[t], 0, 0, 0);
        }
    }

    // combine partial accumulators across the 4 K-quarter waves
#pragma unroll
    for (int t = 0; t < 7; ++t)
#pragma unroll
        for (int e = 0; e < 4; ++e) cacc[wv][lane][t * 4 + e] = acc[t][e];
    __syncthreads();
    if (wv != 0) return;     // no barriers after this point
#pragma unroll
    for (int t = 0; t < 7; ++t)
#pragma unroll
        for (int e = 0; e < 4; ++e)
            acc[t][e] = cacc[0][lane][t * 4 + e] + cacc[1][lane][t * 4 + e] +
                        cacc[2][lane][t * 4 + e] + cacc[3][lane][t * 4 + e];

    // epilogue (wave 0 only): softmax per row; rows lg*4+rr, cols l15+16t
    float ce_acc = 0.f;
#pragma unroll
    for (int rr = 0; rr < 4; ++rr) {
        const int grow = row0 + lg * 4 + rr;
        const int yr = y[grow];
        float m = -3.4e38f;
#pragma unroll
        for (int t = 0; t < 7; ++t) {
            int c = l15 + 16 * t;
            if (c < CN) m = fmaxf(m, acc[t][rr]);
        }
#pragma unroll
        for (int s = 1; s < 16; s <<= 1) m = fmaxf(m, __shfl_xor(m, s));
        float ev[7], ssum = 0.f;
#pragma unroll
        for (int t = 0; t < 7; ++t) {
            int c = l15 + 16 * t;
            ev[t] = (c < CN) ? __expf(acc[t][rr] - m) : 0.f;
            ssum += ev[t];
        }
#pragma unroll
        for (int s = 1; s < 16; s <<= 1) ssum += __shfl_xor(ssum, s);
        const float lse = m + __logf(ssum);
        const float inv = 1.f / ssum;
#pragma unroll
        for (int t = 0; t < 7; ++t) {
            int c = l15 + 16 * t;
            float g = (c < CN) ? (ev[t] * inv - ((c == yr) ? 1.f : 0.f)) : 0.f;
            g_buf[(size_t)grow * GP + c] = f2bf(g);
            if (c == yr) {
                float ce = lse - acc[t][rr];
                ce_acc += ce;
                unsigned long long pk =
                    ((unsigned long long)__float_as_uint(fmaxf(ce, 0.f)) << 32) |
                    (unsigned int)grow;
                atomicMin(&packed[yr], pk);   // argmin ce; ties -> lowest row idx
                atomicAdd(&counts[yr], 1);
            }
        }
    }
#pragma unroll
    for (int s = 1; s < 64; s <<= 1) ce_acc += __shfl_xor(ce_acc, s);
    if (lane == 0) atomicAdd(ce_sum, ce_acc);
}

// ---------------- Gram: M = W^T W (112x112 fp32), K split over 4 waves ----------------
__global__ __launch_bounds__(256) void k_gram(const ushort_t* __restrict__ wB,
                                              float* __restrict__ M) {
    __shared__ float gacc[4][64][4];
    const int tid = threadIdx.x;
    const int lane = tid & 63, wvv = tid >> 6;
    const int c1t = blockIdx.x / 7, c2t = blockIdx.x % 7;
    const int l15 = lane & 15, lg = lane >> 4;
    const ushort_t* pa = wB + (size_t)(c1t * 16 + l15) * KS + lg * 8;
    const ushort_t* pb = wB + (size_t)(c2t * 16 + l15) * KS + lg * 8;
    f32x4 acc = (f32x4){0.f, 0.f, 0.f, 0.f};
#pragma unroll
    for (int i = 0; i < 8; ++i) {
        const size_t o = (size_t)(wvv * 8 + i) * STEPE;
        bf16x8 ah = *(const bf16x8*)(pa + o);
        bf16x8 al = *(const bf16x8*)(pa + o + CP * KS);
        bf16x8 bh = *(const bf16x8*)(pb + o);
        bf16x8 bl = *(const bf16x8*)(pb + o + CP * KS);
        acc = __builtin_amdgcn_mfma_f32_16x16x32_bf16(ah, bh, acc, 0, 0, 0);
        acc = __builtin_amdgcn_mfma_f32_16x16x32_bf16(ah, bl, acc, 0, 0, 0);
        acc = __builtin_amdgcn_mfma_f32_16x16x32_bf16(al, bh, acc, 0, 0, 0);
    }
#pragma unroll
    for (int e = 0; e < 4; ++e) gacc[wvv][lane][e] = acc[e];
    __syncthreads();
    if (tid < 64) {
#pragma unroll
        for (int e = 0; e < 4; ++e) {
            float s = gacc[0][tid][e] + gacc[1][tid][e] + gacc[2][tid][e] + gacc[3][tid][e];
            int row = (tid >> 4) * 4 + e, col = tid & 15;
            M[(size_t)(c1t * 16 + row) * CP + c2t * 16 + col] = s;
        }
    }
}

// ---------------- partial class sums: 8-deep row prefetch ----------------
__global__ __launch_bounds__(256) void k_psum(const int* __restrict__ y,
        const ushort_t* __restrict__ g_buf, float* __restrict__ partial) {
    __shared__ float acc[2][CN][CP];   // 89.6 KB
    const int tid = threadIdx.x;
    const int team = tid >> 7, j = tid & 127;
    float* af = (float*)acc;
    for (int i = tid; i < 2 * CN * CP; i += 256) af[i] = 0.f;
    __syncthreads();
    const int rbase = blockIdx.x * PSR + team;   // team rows: rbase + 2*i
    for (int ch = 0; ch < PSR / 2; ch += 8) {
        ushort_t v[8];
        int cl[8];
#pragma unroll
        for (int q = 0; q < 8; ++q) {
            const int row = rbase + (ch + q) * 2;
            cl[q] = y[row];
            v[q] = (j < CP) ? g_buf[(size_t)row * GP + j] : (ushort_t)0;
        }
#pragma unroll
        for (int q = 0; q < 8; ++q)
            if (j < CP) acc[team][cl[q]][j] += bf2f(v[q]);
    }
    __syncthreads();
    float* out = partial + (size_t)blockIdx.x * (CN * CP);
    for (int i = tid; i < CN * CP; i += 256) out[i] = af[i] + af[i + CN * CP];
}

// ---------------- reduce partials -> class_sum ----------------
__global__ __launch_bounds__(256) void k_reduce(const float* __restrict__ partial,
                                                float* __restrict__ cls) {
    const int i = blockIdx.x * 256 + threadIdx.x;
    if (i >= CN * CP) return;
    float s = 0.f;
#pragma unroll 8
    for (int b = 0; b < PSB; ++b) s += partial[(size_t)b * (CN * CP) + i];
    cls[i] = s;
}

// ---------------- per-class cosines via symmetric Gram matrix ----------------
__global__ __launch_bounds__(128) void k_class(
    const float* __restrict__ M, const ushort_t* __restrict__ g_buf,
    const float* __restrict__ cls, const int* __restrict__ counts,
    const unsigned long long* __restrict__ packed,
    float* __restrict__ term_sum, int* __restrict__ present) {
    __shared__ float a_s[CP], p_s[CP], n_s[CP];
    __shared__ float wsum[2][5];
    const int c = blockIdx.x, t = threadIdx.x;
    if (counts[c] == 0) return;
    const int anchor = (int)(packed[c] & 0xffffffffULL);
    if (t < CP) {
        float a = bf2f(g_buf[(size_t)anchor * GP + t]);
        float cs = cls[c * CP + t];
        float tot = 0.f;
#pragma unroll 8
        for (int k = 0; k < CN; ++k) tot += cls[k * CP + t];   // coalesced
        a_s[t] = a; p_s[t] = cs - a; n_s[t] = tot - cs;
    }
    __syncthreads();
    float aa = 0, ap = 0, pp = 0, an = 0, nn = 0;
    if (t < CP) {
        float ua = 0, up = 0, un = 0;
#pragma unroll 8
        for (int k = 0; k < CP; ++k) {
            float m = M[(size_t)k * CP + t];   // M symmetric -> coalesced rows
            ua = fmaf(m, a_s[k], ua);
            up = fmaf(m, p_s[k], up);
            un = fmaf(m, n_s[k], un);
        }
        aa = a_s[t] * ua; ap = a_s[t] * up; pp = p_s[t] * up;
        an = a_s[t] * un; nn = n_s[t] * un;
    }
#pragma unroll
    for (int s = 1; s < 64; s <<= 1) {
        aa += __shfl_xor(aa, s); ap += __shfl_xor(ap, s); pp += __shfl_xor(pp, s);
        an += __shfl_xor(an, s); nn += __shfl_xor(nn, s);
    }
    const int wid = t >> 6;
    if ((t & 63) == 0) {
        wsum[wid][0] = aa; wsum[wid][1] = ap; wsum[wid][2] = pp;
        wsum[wid][3] = an; wsum[wid][4] = nn;
    }
    __syncthreads();
    if (t == 0) {
        aa = wsum[0][0] + wsum[1][0];
        ap = wsum[0][1] + wsum[1][1];
        pp = wsum[0][2] + wsum[1][2];
        an = wsum[0][3] + wsum[1][3];
        nn = wsum[0][4] + wsum[1][4];
        float na  = sqrtf(fmaxf(aa, 0.f));
        float np_ = sqrtf(fmaxf(pp, 0.f));
        float nn_ = sqrtf(fmaxf(nn, 0.f));
        float cos_ap = ap / (fmaxf(na, 1e-12f) * fmaxf(np_, 1e-12f));
        float cos_an = an / (fmaxf(na, 1e-12f) * fmaxf(nn_, 1e-12f));
        atomicAdd(term_sum, cos_ap - cos_an);
        atomicAdd(present, 1);
    }
}

// ---------------- final scalar ----------------
__global__ void k_final(const float* ce_sum, const float* term_sum,
                        const int* present, float* out) {
    float npres = fmaxf((float)(*present), 1.f);
    out[0] = (*ce_sum) * (1.f / (float)BN) - 2.0f * ((*term_sum) / npres);
}

extern "C" void kernel_launch(void* const* d_in, const int* in_sizes, int n_in,
                              void* d_out, int out_size, void* d_ws, size_t ws_size,
                              hipStream_t stream) {
    const float* x = (const float*)d_in[0];
    const float* W = (const float*)d_in[1];
    const int* y = (const int*)d_in[2];

    char* ws = (char*)d_ws;
    ushort_t* wB      = (ushort_t*)(ws);                    // 458752 B
    ushort_t* g_buf   = (ushort_t*)(ws + 458752);           // 3670016 B
    float*    partial = (float*)(ws + 4128768);             // 2867200 B
    float*    cls     = (float*)(ws + 6995968);             // 44800 B
    float*    M       = (float*)(ws + 7040768);             // 50176 B
    unsigned long long* packed = (unsigned long long*)(ws + 7090944);  // 800 B
    int*      counts  = (int*)(ws + 7091744);               // 400 B
    float*    ce_sum  = (float*)(ws + 7092144);
    float*    term_sum= (float*)(ws + 7092148);
    int*      present = (int*)(ws + 7092152);

    k_prep<<<128, 256, 0, stream>>>(W, wB, packed, counts, ce_sum, term_sum, present);
    k_main<<<BN / 16, THREADS, 0, stream>>>(x, wB, y, g_buf, packed, counts, ce_sum);
    k_gram<<<49, 256, 0, stream>>>(wB, M);
    k_psum<<<PSB, 256, 0, stream>>>(y, g_buf, partial);
    k_reduce<<<(CN * CP + 255) / 256, 256, 0, stream>>>(partial, cls);
    k_class<<<CN, 128, 0, stream>>>(M, g_buf, cls, counts, packed, term_sum, present);
    k_final<<<1, 1, 0, stream>>>(ce_sum, term_sum, present, (float*)d_out);
}

// Round 8
// 158.828 us; speedup vs baseline: 1.4063x; 1.1450x over previous
//
#include <hip/hip_runtime.h>
#include <stdint.h>

#define BN 16384
#define DK 1024
#define CN 100
#define CP 112              // padded col count
#define CP2 224             // hi cols [0,112) + lo cols [112,224) in wB
#define THREADS 256
#define KS 32               // K per step
#define NSTEP (DK / KS)
#define KSPLIT 4            // waves per block, disjoint K quarters
#define WK (DK / KSPLIT)    // 256 K per wave
#define WSTEP (WK / KS)     // 8 steps per wave
#define STEPE (CP2 * KS)    // elements per K-step block in wB = 7168
#define GP 112              // g_buf pitch (bf16 elements)
#define PSB 64              // psum blocks
#define PSR (BN / PSB)      // 256 rows per psum block (128 per team)

typedef __attribute__((ext_vector_type(4))) float f32x4;
typedef __attribute__((ext_vector_type(8))) short bf16x8;
typedef unsigned short ushort_t;
typedef unsigned int uint_t;

__device__ __forceinline__ ushort_t f2bf(float f) {
    uint_t u = __float_as_uint(f);
    uint_t r = u + 0x7FFFu + ((u >> 16) & 1u);   // RNE
    return (ushort_t)(r >> 16);
}
__device__ __forceinline__ float bf2f(ushort_t h) {
    return __uint_as_float(((uint_t)h) << 16);
}
__device__ __forceinline__ float getf(const float4& v, int e) {
    return e == 0 ? v.x : e == 1 ? v.y : e == 2 ? v.z : v.w;
}

// ---------------- prep: W -> wB K-blocked [st][c][kk], hi/lo bf16; + inits ----------------
__global__ __launch_bounds__(256) void k_prep(const float* __restrict__ W,
        ushort_t* __restrict__ wB, float* term_sum, int* present) {
    __shared__ float tile[8][CN];
    const int tid = threadIdx.x;
    const int b = blockIdx.x;              // 0..127
    const int st = b >> 2, kq8 = (b & 3) * 8;
    const float* src = W + (size_t)(st * KS + kq8) * CN;   // 800 contiguous floats
    for (int i = tid; i < 8 * CN; i += 256) {
        int kk = i / CN;
        tile[kk][i - kk * CN] = src[i];
    }
    __syncthreads();
    for (int j = tid; j < CP * 8; j += 256) {
        int c = j >> 3, kk = j & 7;
        float v = (c < CN) ? tile[kk][c] : 0.f;
        ushort_t hb = f2bf(v);
        ushort_t lb = f2bf(v - bf2f(hb));
        size_t o = (size_t)st * STEPE + (size_t)c * KS + kq8 + kk;
        wB[o] = hb;
        wB[o + (size_t)CP * KS] = lb;
    }
    if (b == 0 && tid == 0) { *term_sum = 0.f; *present = 0; }
}

// ---------------- main: x@W, K split over 4 waves; epilogue spread over all waves ----------------
__global__ __launch_bounds__(THREADS) void k_main(
    const float* __restrict__ x, const ushort_t* __restrict__ wB,
    const int* __restrict__ y, ushort_t* __restrict__ g_buf,
    float* __restrict__ ce_buf) {

    __shared__ float cacc[KSPLIT][64][29];   // stride 29 (odd) -> conflict-free

    const int tid = threadIdx.x;
    const int lane = tid & 63;
    const int wv = tid >> 6;              // K-quarter 0..3
    const int l15 = lane & 15;
    const int lg = lane >> 4;             // 0..3
    const int row0 = blockIdx.x * 16;

    // A source: row = row0 + l15, k = wv*WK + s*KS + lg*8
    const float* xg = x + (size_t)(row0 + l15) * DK + wv * WK + lg * 8;
    // B source: col = t*16 + l15, same k; hi plane only
    const ushort_t* wg = wB + (size_t)(wv * WSTEP) * STEPE + (size_t)l15 * KS + lg * 8;

    f32x4 acc[7];
#pragma unroll
    for (int t = 0; t < 7; ++t) acc[t] = (f32x4){0.f, 0.f, 0.f, 0.f};

#pragma unroll
    for (int s = 0; s < WSTEP; ++s) {
        float4 xa = *(const float4*)(xg + s * KS);
        float4 xb = *(const float4*)(xg + s * KS + 4);
        bf16x8 ah, al;
#pragma unroll
        for (int e = 0; e < 4; ++e) {
            float f0 = getf(xa, e);
            float f1 = getf(xb, e);
            ushort_t h0 = f2bf(f0), h1 = f2bf(f1);
            ushort_t l0 = f2bf(f0 - bf2f(h0)), l1 = f2bf(f1 - bf2f(h1));
            ah[e] = (short)h0; ah[e + 4] = (short)h1;
            al[e] = (short)l0; al[e + 4] = (short)l1;
        }
        const ushort_t* bp = wg + (size_t)s * STEPE;
#pragma unroll
        for (int t = 0; t < 7; ++t) {
            bf16x8 bh = *(const bf16x8*)(bp + t * (16 * KS));
            acc[t] = __builtin_amdgcn_mfma_f32_16x16x32_bf16(ah, bh, acc[t], 0, 0, 0);
            acc[t] = __builtin_amdgcn_mfma_f32_16x16x32_bf16(al, bh, acc[t], 0, 0, 0);
        }
    }

    // combine partial accumulators across the 4 K-quarter waves
#pragma unroll
    for (int t = 0; t < 7; ++t)
#pragma unroll
        for (int e = 0; e < 4; ++e) cacc[wv][lane][t * 4 + e] = acc[t][e];
    __syncthreads();

    // epilogue: wave wv owns row r = lg*4 + wv (one row per 16-lane group, no serial loop)
    float pv[7];
#pragma unroll
    for (int t = 0; t < 7; ++t)
        pv[t] = cacc[0][lane][t * 4 + wv] + cacc[1][lane][t * 4 + wv] +
                cacc[2][lane][t * 4 + wv] + cacc[3][lane][t * 4 + wv];

    const int grow = row0 + lg * 4 + wv;
    const int yr = y[grow];
    float m = -3.4e38f;
#pragma unroll
    for (int t = 0; t < 7; ++t) {
        int c = l15 + 16 * t;
        if (c < CN) m = fmaxf(m, pv[t]);
    }
#pragma unroll
    for (int s = 1; s < 16; s <<= 1) m = fmaxf(m, __shfl_xor(m, s));
    float ev[7], ssum = 0.f;
#pragma unroll
    for (int t = 0; t < 7; ++t) {
        int c = l15 + 16 * t;
        ev[t] = (c < CN) ? __expf(pv[t] - m) : 0.f;
        ssum += ev[t];
    }
#pragma unroll
    for (int s = 1; s < 16; s <<= 1) ssum += __shfl_xor(ssum, s);
    const float lse = m + __logf(ssum);
    const float inv = 1.f / ssum;
#pragma unroll
    for (int t = 0; t < 7; ++t) {
        int c = l15 + 16 * t;
        float g = (c < CN) ? (ev[t] * inv - ((c == yr) ? 1.f : 0.f)) : 0.f;
        g_buf[(size_t)grow * GP + c] = f2bf(g);
        if (c == yr) ce_buf[grow] = lse - pv[t];
    }
}

// ---------------- anchor/counts/ce_sum: one block, LDS atomics only ----------------
__global__ __launch_bounds__(1024) void k_anchor(const int* __restrict__ y,
        const float* __restrict__ ce_buf, unsigned long long* __restrict__ packed,
        int* __restrict__ counts, float* __restrict__ ce_sum) {
    __shared__ unsigned long long lp[CN];
    __shared__ int lc[CN];
    __shared__ float lsum[16];
    const int tid = threadIdx.x;
    if (tid < CN) { lp[tid] = ~0ULL; lc[tid] = 0; }
    __syncthreads();
    float se = 0.f;
#pragma unroll
    for (int it = 0; it < BN / 1024; ++it) {
        const int i = tid + it * 1024;
        const int yr = y[i];
        const float ce = ce_buf[i];
        se += ce;
        unsigned long long pk =
            ((unsigned long long)__float_as_uint(fmaxf(ce, 0.f)) << 32) | (unsigned int)i;
        atomicMin(&lp[yr], pk);   // LDS atomic: min ce, ties -> lowest idx
        atomicAdd(&lc[yr], 1);
    }
#pragma unroll
    for (int s = 1; s < 64; s <<= 1) se += __shfl_xor(se, s);
    if ((tid & 63) == 0) lsum[tid >> 6] = se;
    __syncthreads();
    if (tid < CN) { packed[tid] = lp[tid]; counts[tid] = lc[tid]; }
    if (tid == 0) {
        float t = 0.f;
#pragma unroll
        for (int w = 0; w < 16; ++w) t += lsum[w];
        *ce_sum = t;
    }
}

// ---------------- Gram: M = W^T W (112x112 fp32), K split over 4 waves ----------------
__global__ __launch_bounds__(256) void k_gram(const ushort_t* __restrict__ wB,
                                              float* __restrict__ M) {
    __shared__ float gacc[4][64][4];
    const int tid = threadIdx.x;
    const int lane = tid & 63, wvv = tid >> 6;
    const int c1t = blockIdx.x / 7, c2t = blockIdx.x % 7;
    const int l15 = lane & 15, lg = lane >> 4;
    const ushort_t* pa = wB + (size_t)(c1t * 16 + l15) * KS + lg * 8;
    const ushort_t* pb = wB + (size_t)(c2t * 16 + l15) * KS + lg * 8;
    f32x4 acc = (f32x4){0.f, 0.f, 0.f, 0.f};
#pragma unroll
    for (int i = 0; i < 8; ++i) {
        const size_t o = (size_t)(wvv * 8 + i) * STEPE;
        bf16x8 ah = *(const bf16x8*)(pa + o);
        bf16x8 al = *(const bf16x8*)(pa + o + CP * KS);
        bf16x8 bh = *(const bf16x8*)(pb + o);
        bf16x8 bl = *(const bf16x8*)(pb + o + CP * KS);
        acc = __builtin_amdgcn_mfma_f32_16x16x32_bf16(ah, bh, acc, 0, 0, 0);
        acc = __builtin_amdgcn_mfma_f32_16x16x32_bf16(ah, bl, acc, 0, 0, 0);
        acc = __builtin_amdgcn_mfma_f32_16x16x32_bf16(al, bh, acc, 0, 0, 0);
    }
#pragma unroll
    for (int e = 0; e < 4; ++e) gacc[wvv][lane][e] = acc[e];
    __syncthreads();
    if (tid < 64) {
#pragma unroll
        for (int e = 0; e < 4; ++e) {
            float s = gacc[0][tid][e] + gacc[1][tid][e] + gacc[2][tid][e] + gacc[3][tid][e];
            int row = (tid >> 4) * 4 + e, col = tid & 15;
            M[(size_t)(c1t * 16 + row) * CP + c2t * 16 + col] = s;
        }
    }
}

// ---------------- partial class sums: 8-deep row prefetch ----------------
__global__ __launch_bounds__(256) void k_psum(const int* __restrict__ y,
        const ushort_t* __restrict__ g_buf, float* __restrict__ partial) {
    __shared__ float acc[2][CN][CP];   // 89.6 KB
    const int tid = threadIdx.x;
    const int team = tid >> 7, j = tid & 127;
    float* af = (float*)acc;
    for (int i = tid; i < 2 * CN * CP; i += 256) af[i] = 0.f;
    __syncthreads();
    const int rbase = blockIdx.x * PSR + team;   // team rows: rbase + 2*i
    for (int ch = 0; ch < PSR / 2; ch += 8) {
        ushort_t v[8];
        int cl[8];
#pragma unroll
        for (int q = 0; q < 8; ++q) {
            const int row = rbase + (ch + q) * 2;
            cl[q] = y[row];
            v[q] = (j < CP) ? g_buf[(size_t)row * GP + j] : (ushort_t)0;
        }
#pragma unroll
        for (int q = 0; q < 8; ++q)
            if (j < CP) acc[team][cl[q]][j] += bf2f(v[q]);
    }
    __syncthreads();
    float* out = partial + (size_t)blockIdx.x * (CN * CP);
    for (int i = tid; i < CN * CP; i += 256) out[i] = af[i] + af[i + CN * CP];
}

// ---------------- reduce partials -> class_sum ----------------
__global__ __launch_bounds__(256) void k_reduce(const float* __restrict__ partial,
                                                float* __restrict__ cls) {
    const int i = blockIdx.x * 256 + threadIdx.x;
    if (i >= CN * CP) return;
    float s = 0.f;
#pragma unroll 8
    for (int b = 0; b < PSB; ++b) s += partial[(size_t)b * (CN * CP) + i];
    cls[i] = s;
}

// ---------------- per-class cosines via symmetric Gram matrix ----------------
__global__ __launch_bounds__(128) void k_class(
    const float* __restrict__ M, const ushort_t* __restrict__ g_buf,
    const float* __restrict__ cls, const int* __restrict__ counts,
    const unsigned long long* __restrict__ packed,
    float* __restrict__ term_sum, int* __restrict__ present) {
    __shared__ float a_s[CP], p_s[CP], n_s[CP];
    __shared__ float wsum[2][5];
    const int c = blockIdx.x, t = threadIdx.x;
    if (counts[c] == 0) return;
    const int anchor = (int)(packed[c] & 0xffffffffULL);
    if (t < CP) {
        float a = bf2f(g_buf[(size_t)anchor * GP + t]);
        float cs = cls[c * CP + t];
        float tot = 0.f;
#pragma unroll 8
        for (int k = 0; k < CN; ++k) tot += cls[k * CP + t];   // coalesced
        a_s[t] = a; p_s[t] = cs - a; n_s[t] = tot - cs;
    }
    __syncthreads();
    float aa = 0, ap = 0, pp = 0, an = 0, nn = 0;
    if (t < CP) {
        float ua = 0, up = 0, un = 0;
#pragma unroll 8
        for (int k = 0; k < CP; ++k) {
            float m = M[(size_t)k * CP + t];   // M symmetric -> coalesced rows
            ua = fmaf(m, a_s[k], ua);
            up = fmaf(m, p_s[k], up);
            un = fmaf(m, n_s[k], un);
        }
        aa = a_s[t] * ua; ap = a_s[t] * up; pp = p_s[t] * up;
        an = a_s[t] * un; nn = n_s[t] * un;
    }
#pragma unroll
    for (int s = 1; s < 64; s <<= 1) {
        aa += __shfl_xor(aa, s); ap += __shfl_xor(ap, s); pp += __shfl_xor(pp, s);
        an += __shfl_xor(an, s); nn += __shfl_xor(nn, s);
    }
    const int wid = t >> 6;
    if ((t & 63) == 0) {
        wsum[wid][0] = aa; wsum[wid][1] = ap; wsum[wid][2] = pp;
        wsum[wid][3] = an; wsum[wid][4] = nn;
    }
    __syncthreads();
    if (t == 0) {
        aa = wsum[0][0] + wsum[1][0];
        ap = wsum[0][1] + wsum[1][1];
        pp = wsum[0][2] + wsum[1][2];
        an = wsum[0][3] + wsum[1][3];
        nn = wsum[0][4] + wsum[1][4];
        float na  = sqrtf(fmaxf(aa, 0.f));
        float np_ = sqrtf(fmaxf(pp, 0.f));
        float nn_ = sqrtf(fmaxf(nn, 0.f));
        float cos_ap = ap / (fmaxf(na, 1e-12f) * fmaxf(np_, 1e-12f));
        float cos_an = an / (fmaxf(na, 1e-12f) * fmaxf(nn_, 1e-12f));
        atomicAdd(term_sum, cos_ap - cos_an);
        atomicAdd(present, 1);
    }
}

// ---------------- final scalar ----------------
__global__ void k_final(const float* ce_sum, const float* term_sum,
                        const int* present, float* out) {
    float npres = fmaxf((float)(*present), 1.f);
    out[0] = (*ce_sum) * (1.f / (float)BN) - 2.0f * ((*term_sum) / npres);
}

extern "C" void kernel_launch(void* const* d_in, const int* in_sizes, int n_in,
                              void* d_out, int out_size, void* d_ws, size_t ws_size,
                              hipStream_t stream) {
    const float* x = (const float*)d_in[0];
    const float* W = (const float*)d_in[1];
    const int* y = (const int*)d_in[2];

    char* ws = (char*)d_ws;
    ushort_t* wB      = (ushort_t*)(ws);                    // 458752 B
    ushort_t* g_buf   = (ushort_t*)(ws + 458752);           // 3670016 B
    float*    partial = (float*)(ws + 4128768);             // 2867200 B
    float*    cls     = (float*)(ws + 6995968);             // 44800 B
    float*    M       = (float*)(ws + 7040768);             // 50176 B
    unsigned long long* packed = (unsigned long long*)(ws + 7090944);  // 800 B
    int*      counts  = (int*)(ws + 7091744);               // 400 B
    float*    ce_buf  = (float*)(ws + 7092160);             // 65536 B
    float*    ce_sum  = (float*)(ws + 7157696);
    float*    term_sum= (float*)(ws + 7157700);
    int*      present = (int*)(ws + 7157704);

    k_prep<<<128, 256, 0, stream>>>(W, wB, term_sum, present);
    k_main<<<BN / 16, THREADS, 0, stream>>>(x, wB, y, g_buf, ce_buf);
    k_gram<<<49, 256, 0, stream>>>(wB, M);
    k_psum<<<PSB, 256, 0, stream>>>(y, g_buf, partial);
    k_anchor<<<1, 1024, 0, stream>>>(y, ce_buf, packed, counts, ce_sum);
    k_reduce<<<(CN * CP + 255) / 256, 256, 0, stream>>>(partial, cls);
    k_class<<<CN, 128, 0, stream>>>(M, g_buf, cls, counts, packed, term_sum, present);
    k_final<<<1, 1, 0, stream>>>(ce_sum, term_sum, present, (float*)d_out);
}